// Round 12
// baseline (215.879 us; speedup 1.0000x reference)
//
#include <hip/hip_runtime.h>
#include <hip/hip_bf16.h>

#define HID 16
#define DIN 64
#define NK  32
#define NB  8192

#define WSTRIDE 36                       // floats per hinge block: c[16] u[16] A B pad2
#define OUTER_OFF (NK * DIN * WSTRIDE)   // outer-net hinge blocks start here

typedef float v4f __attribute__((ext_vector_type(4)));

// ---- Kernel A: hinge-form weight transform (~3 us, every launch) ----
// inner (k,d):  sum_h w2*relu(w1*x+b1) = A*x + B_d + sum_h u_h*|x + c_h|
// outer (k):    sum_h ow2*relu(ow1*s+ob1) + ob2 = Ao*s + Bo + sum_h uo|s+co|
__global__ void prep_kernel(
    const float* __restrict__ iw1, const float* __restrict__ ib1,
    const float* __restrict__ iw2, const float* __restrict__ ib2,
    const float* __restrict__ ow1, const float* __restrict__ ob1,
    const float* __restrict__ ow2, const float* __restrict__ ob2,
    float* __restrict__ ws)
{
    const int tid = blockIdx.x * 256 + threadIdx.x;
    if (tid < NK * DIN) {
        const float* w1p = iw1 + tid * HID;
        const float* b1p = ib1 + tid * HID;
        const float* w2p = iw2 + tid * HID;
        float* o = ws + tid * WSTRIDE;
        float A = 0.f, B = ib2[tid];
        #pragma unroll
        for (int h = 0; h < HID; ++h) {
            const float w1 = w1p[h], b1 = b1p[h], w2 = w2p[h];
            A = fmaf(0.5f * w2, w1, A);
            B = fmaf(0.5f * w2, b1, B);
            const float aw = fabsf(w1);
            const bool ok = aw > 1e-20f;
            o[h]       = ok ? b1 / w1 : 0.f;
            o[16 + h]  = ok ? 0.5f * w2 * aw : 0.f;
            if (!ok) B = fmaf(0.5f * w2, fabsf(b1), B);
        }
        o[32] = A; o[33] = B; o[34] = 0.f; o[35] = 0.f;
    } else if (tid < NK * DIN + NK) {
        const int k = tid - NK * DIN;
        const float* w1p = ow1 + k * HID;
        const float* b1p = ob1 + k * HID;
        const float* w2p = ow2 + k * HID;
        float* o = ws + OUTER_OFF + k * WSTRIDE;
        float A = 0.f, B = ob2[k];
        #pragma unroll
        for (int h = 0; h < HID; ++h) {
            const float w1 = w1p[h], b1 = b1p[h], w2 = w2p[h];
            A = fmaf(0.5f * w2, w1, A);
            B = fmaf(0.5f * w2, b1, B);
            const float aw = fabsf(w1);
            const bool ok = aw > 1e-20f;
            o[h]       = ok ? b1 / w1 : 0.f;
            o[16 + h]  = ok ? 0.5f * w2 * aw : 0.f;
            if (!ok) B = fmaf(0.5f * w2, fabsf(b1), B);
        }
        o[32] = A; o[33] = B; o[34] = 0.f; o[35] = 0.f;
    }
}

// ---- Kernel B: lane = d, SMALL-STATE variant targeting <=64 VGPRs so the HW
// runs 8 waves/SIMD (occupancy cliff at 64 regs). Hinge weights loaded
// pre-transformed from ws (9 dwordx4 straight into the PW live range — no
// transient blowup). 32 rows/wave in 2 LDS-transpose passes; no prefetch
// arrays — 8-wave TLP hides global-load and DS-tail latency instead.
__global__ __launch_bounds__(256, 8) void kan_main(
    const float* __restrict__ x,
    const float* __restrict__ ws,
    float* __restrict__ out)
{
    __shared__ float lds[4][DIN * 17];

    const int t    = threadIdx.x;
    const int lane = t & 63;
    const int wid  = t >> 6;
    const int k    = blockIdx.x & (NK - 1);
    const int wavebase = (blockIdx.x >> 5) * 128 + wid * 32;   // wave's 32 rows

    // per-lane hinge weights (lane = d): 36 floats, 9 dwordx4
    v4f pw[9];
    {
        const v4f* p = (const v4f*)(ws + (k * DIN + lane) * WSTRIDE);
        #pragma unroll
        for (int q = 0; q < 9; ++q) pw[q] = p[q];
    }
    const float A = pw[8][0], B = pw[8][1];

    float* __restrict__ wb = &lds[wid][lane * 17];
    const int jj  = lane & 15;
    const int pgr = lane >> 4;
    const float* __restrict__ rb = &lds[wid][(pgr * 16) * 17 + jj];
    const int mypass = (lane >> 4) & 1;

    float sk = 0.f;

    #pragma clang loop unroll(disable)
    for (int p = 0; p < 2; ++p) {
        const float* __restrict__ xq = x + (wavebase + p * 16) * DIN + lane;
        // eval 16 rows -> LDS (unroll 4: 4 loads in flight, small live range)
        #pragma unroll 4
        for (int j = 0; j < 16; ++j) {
            const float xv = xq[j * DIN];
            float a0 = fmaf(A, xv, B);
            float a1 = 0.f;
            #pragma unroll
            for (int h = 0; h < HID; h += 2) {
                const float c0 = pw[h >> 2][h & 3];
                const float c1 = pw[(h + 1) >> 2][(h + 1) & 3];
                const float u0 = pw[4 + (h >> 2)][h & 3];
                const float u1 = pw[4 + ((h + 1) >> 2)][(h + 1) & 3];
                a0 = fmaf(fabsf(xv + c0), u0, a0);
                a1 = fmaf(fabsf(xv + c1), u1, a1);
            }
            wb[j] = a0 + a1;
        }
        // transpose-reduce: lane sums its 16-d group for row slot jj
        float s = 0.f;
        #pragma unroll
        for (int i = 0; i < 16; ++i) s += rb[i * 17];
        s += __shfl_xor(s, 16, 64);
        s += __shfl_xor(s, 32, 64);
        sk = (p == mypass) ? s : sk;     // lane keeps the pass owning row lane&31
    }

    // outer net, hinge form, k-uniform -> scalar pipe (1 SGPR per VALU op)
    const float* __restrict__ wo = ws + OUTER_OFF + k * WSTRIDE;
    float oa = 0.f, ob = 0.f;
    #pragma unroll
    for (int h = 0; h < HID; h += 2) {
        oa = fmaf(fabsf(sk + wo[h]),     wo[16 + h],     oa);
        ob = fmaf(fabsf(sk + wo[h + 1]), wo[16 + h + 1], ob);
    }
    oa = fmaf(wo[32], sk, oa);
    ob += wo[33];

    if (lane < 32) {
        out[(wavebase + (lane & 31)) * NK + k] = oa + ob;
    }
}

extern "C" void kernel_launch(void* const* d_in, const int* in_sizes, int n_in,
                              void* d_out, int out_size, void* d_ws, size_t ws_size,
                              hipStream_t stream) {
    const float* x   = (const float*)d_in[0];
    const float* iw1 = (const float*)d_in[1];
    const float* ib1 = (const float*)d_in[2];
    const float* iw2 = (const float*)d_in[3];
    const float* ib2 = (const float*)d_in[4];
    const float* ow1 = (const float*)d_in[5];
    const float* ob1 = (const float*)d_in[6];
    const float* ow2 = (const float*)d_in[7];
    const float* ob2 = (const float*)d_in[8];
    float* ws  = (float*)d_ws;
    float* out = (float*)d_out;

    prep_kernel<<<9, 256, 0, stream>>>(iw1, ib1, iw2, ib2, ow1, ob1, ow2, ob2, ws);
    const int grid = (NB / 128) * NK;   // 64 chunks * 32 k = 2048 blocks
    kan_main<<<grid, 256, 0, stream>>>(x, ws, out);
}